// Round 8
// baseline (134.304 us; speedup 1.0000x reference)
//
#include <hip/hip_runtime.h>
#include <math.h>

// BERT-CRF forward NLL on MI355X — register-only serial recursion, one item
// per 64-lane wave.
//
// Round-7. r5 (fmac-DPP fused matvec, 25.8 VALU/step measured) hit 51 µs but
// sits 85 cyc/step ABOVE the ~6 cyc/instr issue-cadence line — its single
// 16-deep dependent v_fmac chain made the step chain-latency-bound
// (~16 x L_fmac_dpp ~ 240 cyc). This version splits the matvec into FOUR
// independent accumulator chains (round-robin terms, depth 4) + 2-level add
// tree: +3 v_add, chain ~100 cyc < issue ~165 cyc => issue-bound again.
//   v_mul_f32  a_k, x, T[k]  row_ror:k        (k = 0..3)
//   v_fmac_f32 a_k, x, T[4+k] row_ror:4+k     (round-robin, depth 4/chain)
//   a0+=a1; a2+=a3; a0+=a2
// Combine across lane pairs: own+partner == r0+r1 of the equal-input
// permlane swap, x = (r0 + r1) * F.
// Layouts/tables/renorm/prefetch/gold preserved from the PASSING r4/r5:
//   L1 rows hold tag blocks A,B,A,B ; L2 rows A,A,B,B
//   alpha (L1->L2): combine via permlane16_swap ; beta (L2->L1): permlane32.

constexpr int NTAG = 32;
constexpr int TSTART = 30;
constexpr int TSTOP = 31;
constexpr int NB = 1024;
constexpr int NS = 512;

constexpr float LOG2E = 1.44269504088896340736f;
constexpr float LN2   = 0.69314718055994530942f;

typedef unsigned int v2u __attribute__((ext_vector_type(2)));

__device__ __forceinline__ float fexp2(float x) {
#if __has_builtin(__builtin_amdgcn_exp2f)
    return __builtin_amdgcn_exp2f(x);
#else
    return exp2f(x);
#endif
}

// Equal-input permlane swaps: outputs partition {v[j], v[j^K]}, so
// r0 + r1 == v[j] + v[partner] regardless of output order.
__device__ __forceinline__ float swap32_sum(float v) {
    v2u r = __builtin_amdgcn_permlane32_swap(
        __float_as_uint(v), __float_as_uint(v), false, false);
    return __uint_as_float(r.x) + __uint_as_float(r.y);
}
__device__ __forceinline__ float swap16_sum(float v) {
    v2u r = __builtin_amdgcn_permlane16_swap(
        __float_as_uint(v), __float_as_uint(v), false, false);
    return __uint_as_float(r.x) + __uint_as_float(r.y);
}

// 16-term gathered dot product, 4 independent accumulator chains (depth 4),
// terms assigned round-robin, then a 2-level add tree. DPP row_ror fused
// into v_mul/v_fmac (src0 = XV rotated). s_nop 1 guards the
// VALU-write->DPP-read hazard on XV at entry and the VALU-write->permlane
// hazard on A0 at exit.
#define MATVEC4(A0, A1, A2, A3, XV, T)                                        \
    asm("s_nop 1\n\t"                                                         \
        "v_mul_f32 %0, %4, %5\n\t"                                            \
        "v_mul_f32 %1, %4, %6 row_ror:1 row_mask:0xf bank_mask:0xf\n\t"       \
        "v_mul_f32 %2, %4, %7 row_ror:2 row_mask:0xf bank_mask:0xf\n\t"       \
        "v_mul_f32 %3, %4, %8 row_ror:3 row_mask:0xf bank_mask:0xf\n\t"       \
        "v_fmac_f32 %0, %4, %9 row_ror:4 row_mask:0xf bank_mask:0xf\n\t"      \
        "v_fmac_f32 %1, %4, %10 row_ror:5 row_mask:0xf bank_mask:0xf\n\t"     \
        "v_fmac_f32 %2, %4, %11 row_ror:6 row_mask:0xf bank_mask:0xf\n\t"     \
        "v_fmac_f32 %3, %4, %12 row_ror:7 row_mask:0xf bank_mask:0xf\n\t"     \
        "v_fmac_f32 %0, %4, %13 row_ror:8 row_mask:0xf bank_mask:0xf\n\t"     \
        "v_fmac_f32 %1, %4, %14 row_ror:9 row_mask:0xf bank_mask:0xf\n\t"     \
        "v_fmac_f32 %2, %4, %15 row_ror:10 row_mask:0xf bank_mask:0xf\n\t"    \
        "v_fmac_f32 %3, %4, %16 row_ror:11 row_mask:0xf bank_mask:0xf\n\t"    \
        "v_fmac_f32 %0, %4, %17 row_ror:12 row_mask:0xf bank_mask:0xf\n\t"    \
        "v_fmac_f32 %1, %4, %18 row_ror:13 row_mask:0xf bank_mask:0xf\n\t"    \
        "v_fmac_f32 %2, %4, %19 row_ror:14 row_mask:0xf bank_mask:0xf\n\t"    \
        "v_fmac_f32 %3, %4, %20 row_ror:15 row_mask:0xf bank_mask:0xf\n\t"    \
        "v_add_f32 %0, %0, %1\n\t"                                            \
        "v_add_f32 %2, %2, %3\n\t"                                            \
        "v_add_f32 %0, %0, %2\n\t"                                            \
        "s_nop 1"                                                             \
        : "=&v"(A0), "=&v"(A1), "=&v"(A2), "=&v"(A3)                          \
        : "v"(XV), "v"(T[0]), "v"(T[1]), "v"(T[2]), "v"(T[3]),                \
          "v"(T[4]), "v"(T[5]), "v"(T[6]), "v"(T[7]), "v"(T[8]),              \
          "v"(T[9]), "v"(T[10]), "v"(T[11]), "v"(T[12]), "v"(T[13]),          \
          "v"(T[14]), "v"(T[15]))

__global__ __launch_bounds__(64)
void crf_fwd(const float* __restrict__ feats,
             const int*   __restrict__ labels,
             const int*   __restrict__ lengths,
             const float* __restrict__ trans,
             float*       __restrict__ out)
{
    const int j   = threadIdx.x;   // 0..63
    const int j32 = j & 31;
    const int b   = blockIdx.x;

    const int i  = j & 15;          // position within 16-lane row
    const int c1 = j & 16;          // row-parity bit (rows 1,3)
    const int c2 = (j & 32) >> 1;   // half bit as tag-block bit (rows 2,3)

    // Scalar coefficient tables, indexed by rotation amount N:
    //   alpha (L1->L2): src = ((i-N)&15)|c1 , dst-col = i|c2   -> TmS
    //   beta  (L2->L1): src = ((i-N)&15)|c2 , dst-col = i|c1   -> TsS
    float TmS[16], TsS[16];
    #pragma unroll
    for (int N = 0; N < 16; ++N) {
        int s15 = (i - N) & 15;
        TmS[N] = fexp2(trans[((s15 | c1) << 5) + (i | c2)] * LOG2E);
        TsS[N] = fexp2(trans[((s15 | c2) << 5) + (i | c1)] * LOG2E);
    }

    const int len = lengths[b];
    const float* fb = feats  + (size_t)b * NS * NTAG;
    const int*   lb = labels + (size_t)b * NS;

    // labels for this item, staged into registers (coalesced, off the loop)
    int labr[8];
    #pragma unroll
    for (int k = 0; k < 8; ++k)
        labr[k] = lb[(k << 6) + j];

    // Emission-factor / prefetch index per step parity:
    //   after alpha (odd t): layout L2, tag = i|c2
    //   after beta  (even t): layout L1, tag = j32
    const int fxA = i | c2;
    const int fxB = j32;

    // t = 0 : layout L1, lane j holds P0[j32]
    float x = fexp2((fb[j32] + trans[(TSTART << 5) + j32]) * LOG2E);

    int bits0 = __builtin_amdgcn_readfirstlane(__float_as_int(x));
    int e0    = min(max((bits0 >> 23) & 0xFF, 1), 254);
    int kreg  = e0 - 127;
    int creg  = 0;

    // feats prefetch pipeline (8 deep); slot u serves steps t with t%2==(1+u)%2
    float pf[8];
    #pragma unroll
    for (int u = 0; u < 8; ++u) {
        int tt = min(1 + u, NS - 1);
        pf[u] = fb[(size_t)tt * NTAG + ((u & 1) ? fxB : fxA)];
    }

    const int nsteps = len - 1;        // recursion steps t = 1..len-1
    const int nchunk = nsteps >> 3;
    const int rem    = nsteps & 7;
    int t = 1;

    // TBL: TmS (alpha) or TsS (beta); SW: 16 (alpha) or 32 (beta);
    // RN = 1: fold 2^-kreg into emission factor and re-extract kreg.
    #define CRF_STEP(FEAT, TBL, SW, RN)                                       \
    {                                                                         \
        float F_;                                                             \
        if (RN) {                                                             \
            creg += kreg;                                                     \
            F_ = fexp2(fmaf((FEAT), LOG2E, -(float)kreg));                    \
        } else {                                                              \
            F_ = fexp2((FEAT) * LOG2E);                                       \
        }                                                                     \
        float a0_, a1_, a2_, a3_;                                             \
        MATVEC4(a0_, a1_, a2_, a3_, x, TBL);                                  \
        float sum2 = (SW == 16) ? swap16_sum(a0_) : swap32_sum(a0_);          \
        x = sum2 * F_;                                                        \
        if (RN) {                                                             \
            int bits_ = __builtin_amdgcn_readfirstlane(__float_as_int(x));    \
            int e_ = min(max((bits_ >> 23) & 0xFF, 1), 254);                  \
            kreg = e_ - 127;                                                  \
        }                                                                     \
    }

    for (int ci = 0; ci < nchunk; ++ci) {
        #pragma unroll
        for (int u = 0; u < 8; ++u) {
            float feat = pf[u];
            int   tp   = min(t + 8, NS - 1);
            pf[u] = fb[(size_t)tp * NTAG + ((u & 1) ? fxB : fxA)];
            if (u & 1) { CRF_STEP(feat, TsS, 32, 1) }   // beta, renorm
            else       { CRF_STEP(feat, TmS, 16, 0) }   // alpha
            ++t;
        }
    }
    // remainder (<8 steps); pf[u] holds feats for t = 1+8*nchunk+u
    #pragma unroll
    for (int u = 0; u < 7; ++u) {
        if (u < rem) {
            if (u & 1) { CRF_STEP(pf[u], TsS, 32, 1) }
            else       { CRF_STEP(pf[u], TmS, 16, 0) }
            ++t;
        }
    }
    #undef CRF_STEP

    // Every tag appears exactly twice across the 64 lanes in BOTH layouts,
    // so the full 64-lane butterfly gives 2*sum(P); subtract ln2.
    float s = x;
    #pragma unroll
    for (int m = 1; m <= 32; m <<= 1)
        s += __shfl_xor(s, m, 64);
    float fwd = (float)creg * LN2 + logf(s) - LN2;

    // ---- gold score: parallel gather tail (latency-tolerant) ----
    float gold = 0.0f;
    #pragma unroll
    for (int k = 0; k < 8; ++k) {
        int tt = (k << 6) + j;
        if (tt < len) {
            int lab_t = labr[k];
            gold += fb[(size_t)tt * NTAG + lab_t];               // emit
            if (tt > 0)
                gold += trans[(lb[tt - 1] << 5) + lab_t];        // pair
            else
                gold += trans[(TSTART << 5) + lab_t];            // start
            if (tt == len - 1)
                gold += trans[(lab_t << 5) + TSTOP];             // stop
        }
    }
    // reduce gold over all 64 lanes (each (b,t) counted once)
    #pragma unroll
    for (int m = 1; m <= 32; m <<= 1)
        gold += __shfl_xor(gold, m, 64);

    if (j == 0)
        atomicAdd(out, (fwd - gold) * (1.0f / 1024.0f));
}

extern "C" void kernel_launch(void* const* d_in, const int* in_sizes, int n_in,
                              void* d_out, int out_size, void* d_ws, size_t ws_size,
                              hipStream_t stream) {
    const float* feats   = (const float*)d_in[0];
    const int*   labels  = (const int*)d_in[1];
    const int*   lengths = (const int*)d_in[2];
    const float* trans   = (const float*)d_in[3];
    float*       out     = (float*)d_out;

    hipMemsetAsync(out, 0, sizeof(float) * (size_t)out_size, stream);
    crf_fwd<<<dim3(NB), dim3(64), 0, stream>>>(feats, labels, lengths, trans, out);
}